// Round 1
// baseline (1224.108 us; speedup 1.0000x reference)
//
#include <hip/hip_runtime.h>
#include <hip/hip_bf16.h>

#define NN 50000
#define NE 800000

typedef __attribute__((ext_vector_type(8))) short short8;
typedef __attribute__((ext_vector_type(4))) float f32x4;

// ---------- prep: W3T bf16 (transposed, [M=256][K=256]) ----------
__global__ void prep_w3t(const float* __restrict__ W3, __hip_bfloat16* __restrict__ W3T) {
    const int idx4 = (blockIdx.x * 256 + threadIdx.x) * 4;
    const int m = idx4 >> 8;
    const int k = idx4 & 255;
#pragma unroll
    for (int i = 0; i < 4; ++i)
        W3T[m * 256 + k + i] = __float2bfloat16(W3[(k + i) * 256 + m]);
}

// ---------- scatter: agg[dst] += feat[src]; cnt[dst] += 1 ----------
__global__ __launch_bounds__(256) void scatter_kernel(const float* __restrict__ feat,
                                                      const int* __restrict__ ei,
                                                      float* __restrict__ agg,
                                                      float* __restrict__ cnt,
                                                      const int do_cnt) {
    const int f = threadIdx.x & 127;
    const int half = threadIdx.x >> 7;
    const int e0 = blockIdx.x * 32;
    for (int i = 0; i < 32; i += 2) {
        const int e = e0 + i + half;
        const int s = ei[e];
        const int d = ei[NE + e];
        atomicAdd(&agg[d * 128 + f], feat[s * 128 + f]);
        if (do_cnt && f == 0) atomicAdd(&cnt[d], 1.0f);
    }
}

// ---------- SAGE conv: out = relu( (agg/max(cnt,1)) @ Wl + bl + root @ Wr ) ----------
template <bool OUT_BF16>
__global__ __launch_bounds__(256) void conv_kernel(const float* __restrict__ agg,
                                                   const float* __restrict__ cnt,
                                                   const float* __restrict__ root,
                                                   const float* __restrict__ Wl,
                                                   const float* __restrict__ Wr,
                                                   const float* __restrict__ bl,
                                                   void* __restrict__ outp) {
    __shared__ float At[32][256];  // 32 nodes x (agg|root) concat K=256
    const int t = threadIdx.x;
    const int node0 = blockIdx.x * 32;
    {
        const int row = t >> 3, q = t & 7;
        const int node = node0 + row;
        if (node < NN) {
            const float inv = 1.0f / fmaxf(cnt[node], 1.0f);
#pragma unroll
            for (int i = 0; i < 8; ++i) {
                const int k = q * 32 + i * 4;
                float4 v;
                if (k < 128) {
                    v = *(const float4*)&agg[node * 128 + k];
                    v.x *= inv; v.y *= inv; v.z *= inv; v.w *= inv;
                } else {
                    v = *(const float4*)&root[node * 128 + (k - 128)];
                }
                *(float4*)&At[row][k] = v;
            }
        } else {
#pragma unroll
            for (int i = 0; i < 8; ++i) {
                const int k = q * 32 + i * 4;
                *(float4*)&At[row][k] = make_float4(0.f, 0.f, 0.f, 0.f);
            }
        }
    }
    __syncthreads();

    const int c = t & 31, r = t >> 5;  // c: col group, r: node group (0..7)
    float acc[4][4] = {};
#pragma unroll
    for (int h = 0; h < 2; ++h) {
        const float* __restrict__ W = h ? Wr : Wl;
        const int kb = h * 128;
        for (int k4 = 0; k4 < 128; k4 += 4) {
            float4 a[4];
#pragma unroll
            for (int u = 0; u < 4; ++u)
                a[u] = *(const float4*)&At[r + 8 * u][kb + k4];
#pragma unroll
            for (int kk = 0; kk < 4; ++kk) {
                float wv[4];
#pragma unroll
                for (int v = 0; v < 4; ++v)
                    wv[v] = W[(k4 + kk) * 128 + c + 32 * v];
#pragma unroll
                for (int u = 0; u < 4; ++u) {
                    const float av = reinterpret_cast<const float*>(&a[u])[kk];
#pragma unroll
                    for (int v = 0; v < 4; ++v)
                        acc[u][v] = fmaf(av, wv[v], acc[u][v]);
                }
            }
        }
    }
#pragma unroll
    for (int v = 0; v < 4; ++v) {
        const int col = c + 32 * v;
        const float bv = bl[col];
#pragma unroll
        for (int u = 0; u < 4; ++u) {
            const int node = node0 + r + 8 * u;
            if (node < NN) {
                const float val = fmaxf(acc[u][v] + bv, 0.0f);
                if (OUT_BF16)
                    ((__hip_bfloat16*)outp)[node * 128 + col] = __float2bfloat16(val);
                else
                    ((float*)outp)[node * 128 + col] = val;
            }
        }
    }
}

// ---------- edge MLP: pred[e] = W4 . relu([h2[src];h2[dst]] @ W3 + b3) + b4 ----------
__global__ __launch_bounds__(256) void edge_mlp_kernel(const int* __restrict__ ei,
                                                       const __hip_bfloat16* __restrict__ h2b,
                                                       const __hip_bfloat16* __restrict__ w3t,
                                                       const float* __restrict__ b3,
                                                       const float* __restrict__ W4,
                                                       const float* __restrict__ b4,
                                                       float* __restrict__ out) {
    __shared__ __align__(16) char Abuf[64 * 512];  // 64 edges x 256 bf16 (swizzled)
    __shared__ float psum[4][64];
    const int t = threadIdx.x;
    const int e0 = blockIdx.x * 64;
    // stage gathered edge features into LDS (XOR swizzle on 16B units)
    {
        const int el = t >> 2, part = t & 3;
        const int e = e0 + el;
        const int node = ei[(part < 2 ? 0 : NE) + e];
        const char* srcp = (const char*)(h2b + node * 128 + (part & 1) * 64);
        const int sw = (el & 7) << 4;
#pragma unroll
        for (int i = 0; i < 8; ++i) {
            const int inner = part * 128 + i * 16;
            *(uint4*)(Abuf + el * 512 + (inner ^ sw)) = *(const uint4*)(srcp + i * 16);
        }
    }
    __syncthreads();

    const int w = t >> 6, l = t & 63;
    const int lr = l & 15, lg = l >> 4;
    const int wc = w * 64;  // this wave's M-column base
    f32x4 acc[4][4] = {};   // [edge subtile][col subtile]
    for (int ks = 0; ks < 8; ++ks) {
        short8 af[4], bf[4];
        const int innerA = ks * 64 + lg * 16;
#pragma unroll
        for (int et = 0; et < 4; ++et) {
            const int el = et * 16 + lr;
            af[et] = *(const short8*)(Abuf + el * 512 + (innerA ^ ((el & 7) << 4)));
        }
        const int kidx = ks * 32 + lg * 8;
#pragma unroll
        for (int ct = 0; ct < 4; ++ct) {
            const int col = wc + ct * 16 + lr;
            bf[ct] = *(const short8*)(w3t + col * 256 + kidx);
        }
#pragma unroll
        for (int et = 0; et < 4; ++et)
#pragma unroll
            for (int ct = 0; ct < 4; ++ct)
                acc[et][ct] = __builtin_amdgcn_mfma_f32_16x16x32_bf16(af[et], bf[ct], acc[et][ct], 0, 0, 0);
    }
    // epilogue: hidden = relu(acc + b3); partial = sum_m W4[m]*hidden
    float ps[4][4] = {};
#pragma unroll
    for (int ct = 0; ct < 4; ++ct) {
        const int col = wc + ct * 16 + lr;
        const float b3v = b3[col];
        const float w4v = W4[col];
#pragma unroll
        for (int et = 0; et < 4; ++et)
#pragma unroll
            for (int j = 0; j < 4; ++j) {
                const float hv = fmaxf(acc[et][ct][j] + b3v, 0.0f);
                ps[et][j] = fmaf(w4v, hv, ps[et][j]);
            }
    }
#pragma unroll
    for (int et = 0; et < 4; ++et)
#pragma unroll
        for (int j = 0; j < 4; ++j) {
            float v = ps[et][j];
            v += __shfl_xor(v, 1);
            v += __shfl_xor(v, 2);
            v += __shfl_xor(v, 4);
            v += __shfl_xor(v, 8);
            ps[et][j] = v;
        }
    if (lr == 0) {
#pragma unroll
        for (int et = 0; et < 4; ++et)
#pragma unroll
            for (int j = 0; j < 4; ++j)
                psum[w][et * 16 + lg * 4 + j] = ps[et][j];
    }
    __syncthreads();
    if (t < 64) {
        out[e0 + t] = psum[0][t] + psum[1][t] + psum[2][t] + psum[3][t] + b4[0];
    }
}

extern "C" void kernel_launch(void* const* d_in, const int* in_sizes, int n_in,
                              void* d_out, int out_size, void* d_ws, size_t ws_size,
                              hipStream_t stream) {
    const float* x   = (const float*)d_in[0];
    const int* ei    = (const int*)d_in[1];
    const float* W1l = (const float*)d_in[2];
    const float* b1l = (const float*)d_in[3];
    const float* W1r = (const float*)d_in[4];
    const float* W2l = (const float*)d_in[5];
    const float* b2l = (const float*)d_in[6];
    const float* W2r = (const float*)d_in[7];
    const float* W3  = (const float*)d_in[8];
    const float* b3  = (const float*)d_in[9];
    const float* W4  = (const float*)d_in[10];
    const float* b4  = (const float*)d_in[11];
    float* out = (float*)d_out;

    char* ws = (char*)d_ws;
    float* cnt          = (float*)(ws);              // 200000 B
    float* agg          = (float*)(ws + 200704);     // 25.6 MB
    float* h1           = (float*)(ws + 25800704);   // 25.6 MB
    __hip_bfloat16* h2b = (__hip_bfloat16*)(ws + 51400704);  // 12.8 MB
    __hip_bfloat16* w3t = (__hip_bfloat16*)(ws + 64200704);  // 128 KB

    hipMemsetAsync(cnt, 0, NN * sizeof(float), stream);
    hipMemsetAsync(agg, 0, (size_t)NN * 128 * sizeof(float), stream);
    prep_w3t<<<64, 256, 0, stream>>>(W3, w3t);
    scatter_kernel<<<NE / 32, 256, 0, stream>>>(x, ei, agg, cnt, 1);
    conv_kernel<false><<<(NN + 31) / 32, 256, 0, stream>>>(agg, cnt, x, W1l, W1r, b1l, (void*)h1);
    hipMemsetAsync(agg, 0, (size_t)NN * 128 * sizeof(float), stream);
    scatter_kernel<<<NE / 32, 256, 0, stream>>>(h1, ei, agg, cnt, 0);
    conv_kernel<true><<<(NN + 31) / 32, 256, 0, stream>>>(agg, cnt, h1, W2l, W2r, b2l, (void*)h2b);
    edge_mlp_kernel<<<NE / 64, 256, 0, stream>>>(ei, h2b, w3t, b3, W4, b4, out);
}

// Round 2
// 807.951 us; speedup vs baseline: 1.5151x; 1.5151x over previous
//
#include <hip/hip_runtime.h>
#include <hip/hip_bf16.h>

#define NN 50000
#define NE 800000

typedef __attribute__((ext_vector_type(8))) short short8;
typedef __attribute__((ext_vector_type(4))) float f32x4;

// ---------- prep: W3T bf16 (transposed, [M=256][K=256]) ----------
__global__ void prep_w3t(const float* __restrict__ W3, __hip_bfloat16* __restrict__ W3T) {
    const int idx4 = (blockIdx.x * 256 + threadIdx.x) * 4;
    const int m = idx4 >> 8;
    const int k = idx4 & 255;
#pragma unroll
    for (int i = 0; i < 4; ++i)
        W3T[m * 256 + k + i] = __float2bfloat16(W3[(k + i) * 256 + m]);
}

// ---------- CSR build ----------
__global__ __launch_bounds__(256) void hist_kernel(const int* __restrict__ ei,
                                                   int* __restrict__ cnt) {
    for (int e = blockIdx.x * 256 + threadIdx.x; e < NE; e += gridDim.x * 256)
        atomicAdd(&cnt[ei[NE + e]], 1);
}

__global__ __launch_bounds__(1024) void scan_kernel(const int* __restrict__ cnt,
                                                    int* __restrict__ off) {
    __shared__ int part[1024];
    const int t = threadIdx.x;
    const int CHUNK = 49;  // 1024*49 >= 50000
    const int base = t * CHUNK;
    int s = 0;
    for (int i = 0; i < CHUNK; ++i)
        if (base + i < NN) s += cnt[base + i];
    part[t] = s;
    __syncthreads();
    for (int d = 1; d < 1024; d <<= 1) {
        int v = (t >= d) ? part[t - d] : 0;
        __syncthreads();
        part[t] += v;
        __syncthreads();
    }
    int run = (t > 0) ? part[t - 1] : 0;
    for (int i = 0; i < CHUNK; ++i)
        if (base + i < NN) {
            off[base + i] = run;
            run += cnt[base + i];
        }
    if (t == 1023) off[NN] = part[1023];
}

__global__ __launch_bounds__(256) void fill_kernel(const int* __restrict__ ei,
                                                   int* __restrict__ cursor,
                                                   int* __restrict__ ssrc) {
    for (int e = blockIdx.x * 256 + threadIdx.x; e < NE; e += gridDim.x * 256) {
        const int d = ei[NE + e];
        const int p = atomicAdd(&cursor[d], 1);
        ssrc[p] = ei[e];
    }
}

// ---------- gather-mean numerator: agg[n] = sum_{i in [off[n],off[n+1])} feat[ssrc[i]] ----------
__global__ __launch_bounds__(256) void gather_kernel(const float* __restrict__ feat,
                                                     const int* __restrict__ off,
                                                     const int* __restrict__ ssrc,
                                                     float* __restrict__ agg) {
    const int g = threadIdx.x >> 5;
    const int lane = threadIdx.x & 31;
    const int n = blockIdx.x * 8 + g;
    if (n >= NN) return;
    const int b = off[n], e = off[n + 1];
    float4 acc = make_float4(0.f, 0.f, 0.f, 0.f);
    int i = b;
    // 2-deep software pipeline on the index load
    int s_next = (i < e) ? ssrc[i] : 0;
    for (; i < e; ++i) {
        const int s = s_next;
        s_next = (i + 1 < e) ? ssrc[i + 1] : 0;
        const float4 v = *(const float4*)&feat[s * 128 + lane * 4];
        acc.x += v.x; acc.y += v.y; acc.z += v.z; acc.w += v.w;
    }
    *(float4*)&agg[n * 128 + lane * 4] = acc;
}

// ---------- SAGE conv: out = relu( (agg/max(deg,1)) @ Wl + bl + root @ Wr ) ----------
template <bool OUT_BF16>
__global__ __launch_bounds__(256) void conv_kernel(const float* __restrict__ agg,
                                                   const int* __restrict__ cnt,
                                                   const float* __restrict__ root,
                                                   const float* __restrict__ Wl,
                                                   const float* __restrict__ Wr,
                                                   const float* __restrict__ bl,
                                                   void* __restrict__ outp) {
    __shared__ float At[32][256];  // 32 nodes x (agg|root) concat K=256
    const int t = threadIdx.x;
    const int node0 = blockIdx.x * 32;
    {
        const int row = t >> 3, q = t & 7;
        const int node = node0 + row;
        if (node < NN) {
            const float inv = 1.0f / fmaxf((float)cnt[node], 1.0f);
#pragma unroll
            for (int i = 0; i < 8; ++i) {
                const int k = q * 32 + i * 4;
                float4 v;
                if (k < 128) {
                    v = *(const float4*)&agg[node * 128 + k];
                    v.x *= inv; v.y *= inv; v.z *= inv; v.w *= inv;
                } else {
                    v = *(const float4*)&root[node * 128 + (k - 128)];
                }
                *(float4*)&At[row][k] = v;
            }
        } else {
#pragma unroll
            for (int i = 0; i < 8; ++i) {
                const int k = q * 32 + i * 4;
                *(float4*)&At[row][k] = make_float4(0.f, 0.f, 0.f, 0.f);
            }
        }
    }
    __syncthreads();

    const int c = t & 31, r = t >> 5;
    float acc[4][4] = {};
#pragma unroll
    for (int h = 0; h < 2; ++h) {
        const float* __restrict__ W = h ? Wr : Wl;
        const int kb = h * 128;
        for (int k4 = 0; k4 < 128; k4 += 4) {
            float4 a[4];
#pragma unroll
            for (int u = 0; u < 4; ++u)
                a[u] = *(const float4*)&At[r + 8 * u][kb + k4];
#pragma unroll
            for (int kk = 0; kk < 4; ++kk) {
                float wv[4];
#pragma unroll
                for (int v = 0; v < 4; ++v)
                    wv[v] = W[(k4 + kk) * 128 + c + 32 * v];
#pragma unroll
                for (int u = 0; u < 4; ++u) {
                    const float av = reinterpret_cast<const float*>(&a[u])[kk];
#pragma unroll
                    for (int v = 0; v < 4; ++v)
                        acc[u][v] = fmaf(av, wv[v], acc[u][v]);
                }
            }
        }
    }
#pragma unroll
    for (int v = 0; v < 4; ++v) {
        const int col = c + 32 * v;
        const float bv = bl[col];
#pragma unroll
        for (int u = 0; u < 4; ++u) {
            const int node = node0 + r + 8 * u;
            if (node < NN) {
                const float val = fmaxf(acc[u][v] + bv, 0.0f);
                if (OUT_BF16)
                    ((__hip_bfloat16*)outp)[node * 128 + col] = __float2bfloat16(val);
                else
                    ((float*)outp)[node * 128 + col] = val;
            }
        }
    }
}

// ---------- edge MLP: pred[e] = W4 . relu([h2[src];h2[dst]] @ W3 + b3) + b4 ----------
__global__ __launch_bounds__(256) void edge_mlp_kernel(const int* __restrict__ ei,
                                                       const __hip_bfloat16* __restrict__ h2b,
                                                       const __hip_bfloat16* __restrict__ w3t,
                                                       const float* __restrict__ b3,
                                                       const float* __restrict__ W4,
                                                       const float* __restrict__ b4,
                                                       float* __restrict__ out) {
    __shared__ __align__(16) char Abuf[64 * 512];  // 64 edges x 256 bf16 (swizzled)
    __shared__ float psum[4][64];
    const int t = threadIdx.x;
    const int e0 = blockIdx.x * 64;
    {
        const int el = t >> 2, part = t & 3;
        const int e = e0 + el;
        const int node = ei[(part < 2 ? 0 : NE) + e];
        const char* srcp = (const char*)(h2b + node * 128 + (part & 1) * 64);
        const int sw = (el & 7) << 4;
#pragma unroll
        for (int i = 0; i < 8; ++i) {
            const int inner = part * 128 + i * 16;
            *(uint4*)(Abuf + el * 512 + (inner ^ sw)) = *(const uint4*)(srcp + i * 16);
        }
    }
    __syncthreads();

    const int w = t >> 6, l = t & 63;
    const int lr = l & 15, lg = l >> 4;
    const int wc = w * 64;
    f32x4 acc[4][4] = {};
    for (int ks = 0; ks < 8; ++ks) {
        short8 af[4], bf[4];
        const int innerA = ks * 64 + lg * 16;
#pragma unroll
        for (int et = 0; et < 4; ++et) {
            const int el = et * 16 + lr;
            af[et] = *(const short8*)(Abuf + el * 512 + (innerA ^ ((el & 7) << 4)));
        }
        const int kidx = ks * 32 + lg * 8;
#pragma unroll
        for (int ct = 0; ct < 4; ++ct) {
            const int col = wc + ct * 16 + lr;
            bf[ct] = *(const short8*)(w3t + col * 256 + kidx);
        }
#pragma unroll
        for (int et = 0; et < 4; ++et)
#pragma unroll
            for (int ct = 0; ct < 4; ++ct)
                acc[et][ct] = __builtin_amdgcn_mfma_f32_16x16x32_bf16(af[et], bf[ct], acc[et][ct], 0, 0, 0);
    }
    float ps[4][4] = {};
#pragma unroll
    for (int ct = 0; ct < 4; ++ct) {
        const int col = wc + ct * 16 + lr;
        const float b3v = b3[col];
        const float w4v = W4[col];
#pragma unroll
        for (int et = 0; et < 4; ++et)
#pragma unroll
            for (int j = 0; j < 4; ++j) {
                const float hv = fmaxf(acc[et][ct][j] + b3v, 0.0f);
                ps[et][j] = fmaf(w4v, hv, ps[et][j]);
            }
    }
#pragma unroll
    for (int et = 0; et < 4; ++et)
#pragma unroll
        for (int j = 0; j < 4; ++j) {
            float v = ps[et][j];
            v += __shfl_xor(v, 1);
            v += __shfl_xor(v, 2);
            v += __shfl_xor(v, 4);
            v += __shfl_xor(v, 8);
            ps[et][j] = v;
        }
    if (lr == 0) {
#pragma unroll
        for (int et = 0; et < 4; ++et)
#pragma unroll
            for (int j = 0; j < 4; ++j)
                psum[w][et * 16 + lg * 4 + j] = ps[et][j];
    }
    __syncthreads();
    if (t < 64) {
        out[e0 + t] = psum[0][t] + psum[1][t] + psum[2][t] + psum[3][t] + b4[0];
    }
}

extern "C" void kernel_launch(void* const* d_in, const int* in_sizes, int n_in,
                              void* d_out, int out_size, void* d_ws, size_t ws_size,
                              hipStream_t stream) {
    const float* x   = (const float*)d_in[0];
    const int* ei    = (const int*)d_in[1];
    const float* W1l = (const float*)d_in[2];
    const float* b1l = (const float*)d_in[3];
    const float* W1r = (const float*)d_in[4];
    const float* W2l = (const float*)d_in[5];
    const float* b2l = (const float*)d_in[6];
    const float* W2r = (const float*)d_in[7];
    const float* W3  = (const float*)d_in[8];
    const float* b3  = (const float*)d_in[9];
    const float* W4  = (const float*)d_in[10];
    const float* b4  = (const float*)d_in[11];
    float* out = (float*)d_out;

    char* ws = (char*)d_ws;
    int* cnt            = (int*)(ws);                        // 200 KB
    int* off            = (int*)(ws + 200704);               // (NN+1)*4
    int* cursor         = (int*)(ws + 401408);               // NN*4
    int* ssrc           = (int*)(ws + 602112);               // 3.2 MB  (aliased w/ h2b)
    __hip_bfloat16* h2b = (__hip_bfloat16*)(ws + 602112);    // 12.8 MB (alive after ssrc dead)
    float* agg          = (float*)(ws + 13402112);           // 25.6 MB
    float* h1           = (float*)(ws + 39002112);           // 25.6 MB
    __hip_bfloat16* w3t = (__hip_bfloat16*)(ws + 64602112);  // 128 KB

    hipMemsetAsync(cnt, 0, NN * sizeof(int), stream);
    hist_kernel<<<1024, 256, 0, stream>>>(ei, cnt);
    scan_kernel<<<1, 1024, 0, stream>>>(cnt, off);
    hipMemcpyAsync(cursor, off, NN * sizeof(int), hipMemcpyDeviceToDevice, stream);
    fill_kernel<<<1024, 256, 0, stream>>>(ei, cursor, ssrc);
    prep_w3t<<<64, 256, 0, stream>>>(W3, w3t);

    gather_kernel<<<(NN + 7) / 8, 256, 0, stream>>>(x, off, ssrc, agg);
    conv_kernel<false><<<(NN + 31) / 32, 256, 0, stream>>>(agg, cnt, x, W1l, W1r, b1l, (void*)h1);
    gather_kernel<<<(NN + 7) / 8, 256, 0, stream>>>(h1, off, ssrc, agg);
    conv_kernel<true><<<(NN + 31) / 32, 256, 0, stream>>>(agg, cnt, h1, W2l, W2r, b2l, (void*)h2b);
    edge_mlp_kernel<<<NE / 64, 256, 0, stream>>>(ei, h2b, w3t, b3, W4, b4, out);
}

// Round 3
// 678.690 us; speedup vs baseline: 1.8036x; 1.1905x over previous
//
#include <hip/hip_runtime.h>
#include <hip/hip_bf16.h>

#define NN 50000
#define NE 800000

typedef __attribute__((ext_vector_type(8))) short short8;
typedef __attribute__((ext_vector_type(4))) float f32x4;

__device__ inline float bf_lo(unsigned u) { u <<= 16; float f; __builtin_memcpy(&f, &u, 4); return f; }
__device__ inline float bf_hi(unsigned u) { u &= 0xffff0000u; float f; __builtin_memcpy(&f, &u, 4); return f; }

// ---------- prep: wpq bf16 [512 outcols][128 k] ; col<256 -> W3_top col, col>=256 -> W3_bot col ----------
__global__ void prep_wpq(const float* __restrict__ W3, __hip_bfloat16* __restrict__ wpq) {
    const int idx4 = (blockIdx.x * 256 + threadIdx.x) * 4;
    const int c = idx4 >> 7;
    const int k0 = idx4 & 127;
#pragma unroll
    for (int i = 0; i < 4; ++i) {
        const int k = k0 + i;
        const float v = (c < 256) ? W3[k * 256 + c] : W3[(128 + k) * 256 + (c - 256)];
        wpq[c * 128 + k] = __float2bfloat16(v);
    }
}

// ---------- prep: x fp32 -> bf16 table ----------
__global__ void prep_xb(const float* __restrict__ x, __hip_bfloat16* __restrict__ xb) {
    const int idx = (blockIdx.x * 256 + threadIdx.x) * 4;
    if (idx >= NN * 128) return;
    const float4 v = *(const float4*)&x[idx];
    xb[idx + 0] = __float2bfloat16(v.x);
    xb[idx + 1] = __float2bfloat16(v.y);
    xb[idx + 2] = __float2bfloat16(v.z);
    xb[idx + 3] = __float2bfloat16(v.w);
}

// ---------- CSR build ----------
__global__ __launch_bounds__(256) void hist_kernel(const int* __restrict__ ei,
                                                   int* __restrict__ cnt) {
    for (int e = blockIdx.x * 256 + threadIdx.x; e < NE; e += gridDim.x * 256)
        atomicAdd(&cnt[ei[NE + e]], 1);
}

__global__ __launch_bounds__(1024) void scan_kernel(const int* __restrict__ cnt,
                                                    int* __restrict__ off) {
    __shared__ int part[1024];
    const int t = threadIdx.x;
    const int CHUNK = 49;
    const int base = t * CHUNK;
    int s = 0;
    for (int i = 0; i < CHUNK; ++i)
        if (base + i < NN) s += cnt[base + i];
    part[t] = s;
    __syncthreads();
    for (int d = 1; d < 1024; d <<= 1) {
        int v = (t >= d) ? part[t - d] : 0;
        __syncthreads();
        part[t] += v;
        __syncthreads();
    }
    int run = (t > 0) ? part[t - 1] : 0;
    for (int i = 0; i < CHUNK; ++i)
        if (base + i < NN) {
            off[base + i] = run;
            run += cnt[base + i];
        }
    if (t == 1023) off[NN] = part[1023];
}

__global__ __launch_bounds__(256) void fill_kernel(const int* __restrict__ ei,
                                                   int* __restrict__ cursor,
                                                   int* __restrict__ ssrc,
                                                   int* __restrict__ sdst,
                                                   int* __restrict__ seid) {
    for (int e = blockIdx.x * 256 + threadIdx.x; e < NE; e += gridDim.x * 256) {
        const int d = ei[NE + e];
        const int p = atomicAdd(&cursor[d], 1);
        ssrc[p] = ei[e];
        sdst[p] = d;
        seid[p] = e;
    }
}

// ---------- gather-mean numerator from bf16 table: agg[n] = sum feat[ssrc[i]] ----------
__global__ __launch_bounds__(256) void gather_kernel(const __hip_bfloat16* __restrict__ feat,
                                                     const int* __restrict__ off,
                                                     const int* __restrict__ ssrc,
                                                     float* __restrict__ agg) {
    const int g = threadIdx.x >> 5;
    const int lane = threadIdx.x & 31;
    const int n = blockIdx.x * 8 + g;
    if (n >= NN) return;
    const int b = off[n], e = off[n + 1];
    float a0 = 0.f, a1 = 0.f, a2 = 0.f, a3 = 0.f;
    int s_next = (b < e) ? ssrc[b] : 0;
    for (int i = b; i < e; ++i) {
        const int s = s_next;
        s_next = (i + 1 < e) ? ssrc[i + 1] : 0;
        const uint2 u = *(const uint2*)(feat + s * 128 + lane * 4);
        a0 += bf_lo(u.x); a1 += bf_hi(u.x);
        a2 += bf_lo(u.y); a3 += bf_hi(u.y);
    }
    *(float4*)&agg[n * 128 + lane * 4] = make_float4(a0, a1, a2, a3);
}

// ---------- SAGE conv: out_bf16 = relu( (agg/max(deg,1)) @ Wl + bl + root @ Wr ) ----------
template <bool ROOT_BF16>
__global__ __launch_bounds__(256) void conv_kernel(const float* __restrict__ agg,
                                                   const int* __restrict__ cnt,
                                                   const void* __restrict__ rootp,
                                                   const float* __restrict__ Wl,
                                                   const float* __restrict__ Wr,
                                                   const float* __restrict__ bl,
                                                   __hip_bfloat16* __restrict__ outp) {
    __shared__ float At[32][256];
    const int t = threadIdx.x;
    const int node0 = blockIdx.x * 32;
    {
        const int row = t >> 3, q = t & 7;
        const int node = node0 + row;
        if (node < NN) {
            const float inv = 1.0f / fmaxf((float)cnt[node], 1.0f);
#pragma unroll
            for (int i = 0; i < 8; ++i) {
                const int k = q * 32 + i * 4;
                float4 v;
                if (k < 128) {
                    v = *(const float4*)&agg[node * 128 + k];
                    v.x *= inv; v.y *= inv; v.z *= inv; v.w *= inv;
                } else if (ROOT_BF16) {
                    const uint2 u = *(const uint2*)((const __hip_bfloat16*)rootp + node * 128 + (k - 128));
                    v = make_float4(bf_lo(u.x), bf_hi(u.x), bf_lo(u.y), bf_hi(u.y));
                } else {
                    v = *(const float4*)&((const float*)rootp)[node * 128 + (k - 128)];
                }
                *(float4*)&At[row][k] = v;
            }
        } else {
#pragma unroll
            for (int i = 0; i < 8; ++i) {
                const int k = q * 32 + i * 4;
                *(float4*)&At[row][k] = make_float4(0.f, 0.f, 0.f, 0.f);
            }
        }
    }
    __syncthreads();

    const int c = t & 31, r = t >> 5;
    float acc[4][4] = {};
#pragma unroll
    for (int h = 0; h < 2; ++h) {
        const float* __restrict__ W = h ? Wr : Wl;
        const int kb = h * 128;
        for (int k4 = 0; k4 < 128; k4 += 4) {
            float4 a[4];
#pragma unroll
            for (int u = 0; u < 4; ++u)
                a[u] = *(const float4*)&At[r + 8 * u][kb + k4];
#pragma unroll
            for (int kk = 0; kk < 4; ++kk) {
                float wv[4];
#pragma unroll
                for (int v = 0; v < 4; ++v)
                    wv[v] = W[(k4 + kk) * 128 + c + 32 * v];
#pragma unroll
                for (int u = 0; u < 4; ++u) {
                    const float av = reinterpret_cast<const float*>(&a[u])[kk];
#pragma unroll
                    for (int v = 0; v < 4; ++v)
                        acc[u][v] = fmaf(av, wv[v], acc[u][v]);
                }
            }
        }
    }
#pragma unroll
    for (int v = 0; v < 4; ++v) {
        const int col = c + 32 * v;
        const float bv = bl[col];
#pragma unroll
        for (int u = 0; u < 4; ++u) {
            const int node = node0 + r + 8 * u;
            if (node < NN)
                outp[node * 128 + col] = __float2bfloat16(fmaxf(acc[u][v] + bv, 0.0f));
        }
    }
}

// ---------- PQ GEMM: pqb[n][0:256]=h2[n]@W3_top ; pqb[n][256:512]=h2[n]@W3_bot + b3 ----------
__global__ __launch_bounds__(256) void pq_gemm(const __hip_bfloat16* __restrict__ h2b,
                                               const __hip_bfloat16* __restrict__ wpq,
                                               const float* __restrict__ b3,
                                               __hip_bfloat16* __restrict__ pqb) {
    __shared__ __align__(16) char A[64 * 256];  // 64 rows x 128 bf16, XOR-swizzled
    const int t = threadIdx.x;
    const int n0 = blockIdx.x * 64;
    {
        const int row = t >> 2, part = t & 3;
        const int node = n0 + row;
        const int sw = (row & 7) << 4;
#pragma unroll
        for (int i = 0; i < 4; ++i) {
            const int inner = part * 64 + i * 16;
            uint4 v = make_uint4(0u, 0u, 0u, 0u);
            if (node < NN) v = *(const uint4*)((const char*)(h2b + node * 128) + inner);
            *(uint4*)(A + row * 256 + (inner ^ sw)) = v;
        }
    }
    __syncthreads();

    const int w = t >> 6, l = t & 63;
    const int lr = l & 15, lg = l >> 4;
    const int cb = w * 128;
    f32x4 acc[4][8] = {};
    for (int ks = 0; ks < 4; ++ks) {
        short8 af[4], bf[8];
        const int innerA = ks * 64 + lg * 16;
#pragma unroll
        for (int rt = 0; rt < 4; ++rt) {
            const int row = rt * 16 + lr;
            af[rt] = *(const short8*)(A + row * 256 + (innerA ^ ((row & 7) << 4)));
        }
        const int kidx = ks * 32 + lg * 8;
#pragma unroll
        for (int ct = 0; ct < 8; ++ct) {
            const int col = cb + ct * 16 + lr;
            bf[ct] = *(const short8*)(wpq + col * 128 + kidx);
        }
#pragma unroll
        for (int rt = 0; rt < 4; ++rt)
#pragma unroll
            for (int ct = 0; ct < 8; ++ct)
                acc[rt][ct] = __builtin_amdgcn_mfma_f32_16x16x32_bf16(af[rt], bf[ct], acc[rt][ct], 0, 0, 0);
    }
#pragma unroll
    for (int ct = 0; ct < 8; ++ct) {
        const int col = cb + ct * 16 + lr;
        const float badd = (col >= 256) ? b3[col - 256] : 0.f;
#pragma unroll
        for (int rt = 0; rt < 4; ++rt)
#pragma unroll
            for (int j = 0; j < 4; ++j) {
                const int node = n0 + rt * 16 + lg * 4 + j;
                if (node < NN)
                    pqb[(size_t)node * 512 + col] = __float2bfloat16(acc[rt][ct][j] + badd);
            }
    }
}

// ---------- edge: out[eid] = W4 . relu(P[src] + Q'[dst]) + b4, sorted-by-dst order ----------
__global__ __launch_bounds__(256) void edge_kernel(const int* __restrict__ ssrc,
                                                   const int* __restrict__ sdst,
                                                   const int* __restrict__ seid,
                                                   const __hip_bfloat16* __restrict__ pqb,
                                                   const float* __restrict__ W4,
                                                   const float* __restrict__ b4,
                                                   float* __restrict__ out) {
    const int i = threadIdx.x & 7;   // lane in 8-lane group
    const int g = threadIdx.x >> 3;  // 32 groups per block
    float w4r[4][8];
#pragma unroll
    for (int j = 0; j < 4; ++j)
#pragma unroll
        for (int u = 0; u < 8; ++u)
            w4r[j][u] = W4[i * 8 + j * 64 + u];
    const float b4v = b4[0];
    for (int p = blockIdx.x * 32 + g; p < NE; p += gridDim.x * 32) {
        const int s = ssrc[p], d = sdst[p], eid = seid[p];
        const char* Pp = (const char*)(pqb + (size_t)s * 512 + i * 8);
        const char* Qp = (const char*)(pqb + (size_t)d * 512 + 256 + i * 8);
        float acc = 0.f;
#pragma unroll
        for (int j = 0; j < 4; ++j) {
            const uint4 pv = *(const uint4*)(Pp + j * 128);
            const uint4 qv = *(const uint4*)(Qp + j * 128);
            const unsigned pa[4] = {pv.x, pv.y, pv.z, pv.w};
            const unsigned qa[4] = {qv.x, qv.y, qv.z, qv.w};
#pragma unroll
            for (int q4 = 0; q4 < 4; ++q4) {
                const float hlo = fmaxf(bf_lo(pa[q4]) + bf_lo(qa[q4]), 0.f);
                const float hhi = fmaxf(bf_hi(pa[q4]) + bf_hi(qa[q4]), 0.f);
                acc = fmaf(hlo, w4r[j][q4 * 2], acc);
                acc = fmaf(hhi, w4r[j][q4 * 2 + 1], acc);
            }
        }
        acc += __shfl_xor(acc, 1);
        acc += __shfl_xor(acc, 2);
        acc += __shfl_xor(acc, 4);
        if (i == 0) out[eid] = acc + b4v;
    }
}

extern "C" void kernel_launch(void* const* d_in, const int* in_sizes, int n_in,
                              void* d_out, int out_size, void* d_ws, size_t ws_size,
                              hipStream_t stream) {
    const float* x   = (const float*)d_in[0];
    const int* ei    = (const int*)d_in[1];
    const float* W1l = (const float*)d_in[2];
    const float* b1l = (const float*)d_in[3];
    const float* W1r = (const float*)d_in[4];
    const float* W2l = (const float*)d_in[5];
    const float* b2l = (const float*)d_in[6];
    const float* W2r = (const float*)d_in[7];
    const float* W3  = (const float*)d_in[8];
    const float* b3  = (const float*)d_in[9];
    const float* W4  = (const float*)d_in[10];
    const float* b4  = (const float*)d_in[11];
    float* out = (float*)d_out;

    char* ws = (char*)d_ws;
    int* cnt            = (int*)(ws);                        // 200 KB
    int* off            = (int*)(ws + 200704);
    int* cursor         = (int*)(ws + 401408);
    int* ssrc           = (int*)(ws + 602112);               // 3.2 MB
    int* sdst           = (int*)(ws + 3802112);              // 3.2 MB
    int* seid           = (int*)(ws + 7002112);              // 3.2 MB
    __hip_bfloat16* xb  = (__hip_bfloat16*)(ws + 10202112);  // 12.8 MB (dead after gather1)
    __hip_bfloat16* h1b = (__hip_bfloat16*)(ws + 23002112);  // 12.8 MB (dead after conv2)
    float* agg          = (float*)(ws + 35802112);           // 25.6 MB (dead after conv2)
    __hip_bfloat16* h2b = (__hip_bfloat16*)(ws + 61402112);  // 12.8 MB
    __hip_bfloat16* pqb = (__hip_bfloat16*)(ws + 10202112);  // 51.2 MB, overlays xb+h1b+agg
    __hip_bfloat16* wpq = (__hip_bfloat16*)(ws + 74202112);  // 128 KB

    hipMemsetAsync(cnt, 0, NN * sizeof(int), stream);
    hist_kernel<<<1024, 256, 0, stream>>>(ei, cnt);
    scan_kernel<<<1, 1024, 0, stream>>>(cnt, off);
    hipMemcpyAsync(cursor, off, NN * sizeof(int), hipMemcpyDeviceToDevice, stream);
    fill_kernel<<<1024, 256, 0, stream>>>(ei, cursor, ssrc, sdst, seid);
    prep_wpq<<<64, 256, 0, stream>>>(W3, wpq);
    prep_xb<<<(NN * 128 / 4 + 255) / 256, 256, 0, stream>>>(x, xb);

    gather_kernel<<<(NN + 7) / 8, 256, 0, stream>>>(xb, off, ssrc, agg);
    conv_kernel<false><<<(NN + 31) / 32, 256, 0, stream>>>(agg, cnt, (const void*)x, W1l, W1r, b1l, h1b);
    gather_kernel<<<(NN + 7) / 8, 256, 0, stream>>>(h1b, off, ssrc, agg);
    conv_kernel<true><<<(NN + 31) / 32, 256, 0, stream>>>(agg, cnt, (const void*)h1b, W2l, W2r, b2l, h2b);
    pq_gemm<<<(NN + 63) / 64, 256, 0, stream>>>(h2b, wpq, b3, pqb);
    edge_kernel<<<2048, 256, 0, stream>>>(ssrc, sdst, seid, pqb, W4, b4, out);
}

// Round 5
// 595.304 us; speedup vs baseline: 2.0563x; 1.1401x over previous
//
#include <hip/hip_runtime.h>
#include <hip/hip_bf16.h>

#define NN 50000
#define NE 800000
#define SCAN_G ((NN + 255) / 256)  // 196

typedef __attribute__((ext_vector_type(8))) short short8;
typedef __attribute__((ext_vector_type(4))) float f32x4;

__device__ inline float bf_lo(unsigned u) { u <<= 16; float f; __builtin_memcpy(&f, &u, 4); return f; }
__device__ inline float bf_hi(unsigned u) { u &= 0xffff0000u; float f; __builtin_memcpy(&f, &u, 4); return f; }

// ---------- prep: wpq bf16 [512 outcols][128 k] ----------
__global__ void prep_wpq(const float* __restrict__ W3, __hip_bfloat16* __restrict__ wpq) {
    const int idx4 = (blockIdx.x * 256 + threadIdx.x) * 4;
    const int c = idx4 >> 7;
    const int k0 = idx4 & 127;
#pragma unroll
    for (int i = 0; i < 4; ++i) {
        const int k = k0 + i;
        const float v = (c < 256) ? W3[k * 256 + c] : W3[(128 + k) * 256 + (c - 256)];
        wpq[c * 128 + k] = __float2bfloat16(v);
    }
}

// ---------- prep: x fp32 -> bf16 table ----------
__global__ void prep_xb(const float* __restrict__ x, __hip_bfloat16* __restrict__ xb) {
    const int idx = (blockIdx.x * 256 + threadIdx.x) * 4;
    if (idx >= NN * 128) return;
    const float4 v = *(const float4*)&x[idx];
    xb[idx + 0] = __float2bfloat16(v.x);
    xb[idx + 1] = __float2bfloat16(v.y);
    xb[idx + 2] = __float2bfloat16(v.z);
    xb[idx + 3] = __float2bfloat16(v.w);
}

// ---------- CSR build ----------
__global__ __launch_bounds__(256) void hist_kernel(const int* __restrict__ ei,
                                                   int* __restrict__ cnt) {
    for (int e = blockIdx.x * 256 + threadIdx.x; e < NE; e += gridDim.x * 256)
        atomicAdd(&cnt[ei[NE + e]], 1);
}

// block-local exclusive scan; off[i] = local exclusive, bsum[b] = block total
__global__ __launch_bounds__(256) void scan_blk(const int* __restrict__ cnt,
                                                int* __restrict__ off,
                                                int* __restrict__ bsum) {
    __shared__ int sm[256];
    const int t = threadIdx.x;
    const int i = blockIdx.x * 256 + t;
    const int v = (i < NN) ? cnt[i] : 0;
    sm[t] = v;
    __syncthreads();
    for (int d = 1; d < 256; d <<= 1) {
        const int add = (t >= d) ? sm[t - d] : 0;
        __syncthreads();
        sm[t] += add;
        __syncthreads();
    }
    if (i < NN) off[i] = sm[t] - v;  // exclusive
    if (t == 255) bsum[blockIdx.x] = sm[255];
}

// single block: exclusive scan of the 196 block sums
__global__ __launch_bounds__(256) void scan_top(int* __restrict__ bsum) {
    __shared__ int sm[256];
    const int t = threadIdx.x;
    const int v = (t < SCAN_G) ? bsum[t] : 0;
    sm[t] = v;
    __syncthreads();
    for (int d = 1; d < 256; d <<= 1) {
        const int add = (t >= d) ? sm[t - d] : 0;
        __syncthreads();
        sm[t] += add;
        __syncthreads();
    }
    if (t < SCAN_G) bsum[t] = sm[t] - v;  // exclusive
}

// off[i] += bsum[block]; also materialize cursor copy and off[NN]
__global__ __launch_bounds__(256) void scan_add(int* __restrict__ off,
                                                int* __restrict__ cursor,
                                                const int* __restrict__ bsum) {
    const int t = threadIdx.x;
    const int i = blockIdx.x * 256 + t;
    if (i < NN) {
        const int v = off[i] + bsum[blockIdx.x];
        off[i] = v;
        cursor[i] = v;
    }
    if (i == NN - 1) off[NN] = NE;
}

__global__ __launch_bounds__(256) void fill_kernel(const int* __restrict__ ei,
                                                   int* __restrict__ cursor,
                                                   int* __restrict__ ssrc,
                                                   int* __restrict__ sdst,
                                                   int* __restrict__ seid) {
    for (int e = blockIdx.x * 256 + threadIdx.x; e < NE; e += gridDim.x * 256) {
        const int d = ei[NE + e];
        const int p = atomicAdd(&cursor[d], 1);
        ssrc[p] = ei[e];
        sdst[p] = d;
        seid[p] = e;
    }
}

// ---------- fused gather-mean + SAGE conv ----------
// out_bf16 = relu( mean_{src in N(n)} featb[src] @ Wl + bl + root[n] @ Wr )
template <bool ROOT_BF16>
__global__ __launch_bounds__(256) void fused_conv(const __hip_bfloat16* __restrict__ featb,
                                                  const int* __restrict__ off,
                                                  const int* __restrict__ ssrc,
                                                  const void* __restrict__ rootp,
                                                  const float* __restrict__ Wl,
                                                  const float* __restrict__ Wr,
                                                  const float* __restrict__ bl,
                                                  __hip_bfloat16* __restrict__ outp) {
    __shared__ float At[32][256];  // 32 nodes x (mean-agg | root) K=256
    const int t = threadIdx.x;
    const int node0 = blockIdx.x * 32;
    const int wv = t >> 6, lane = t & 63;
    // gather phase: 4 waves x 8 rows each = 32 rows; lane covers 2 feats
#pragma unroll
    for (int u = 0; u < 8; ++u) {
        const int row = wv * 8 + u;
        const int n = node0 + row;
        float a0 = 0.f, a1 = 0.f;
        int b = 0, e = 0;
        if (n < NN) { b = off[n]; e = off[n + 1]; }
        int s0 = (b < e) ? ssrc[b] : 0;
        int s1 = (b + 1 < e) ? ssrc[b + 1] : 0;
        int i = b;
        for (; i + 2 <= e; i += 2) {
            const unsigned ua = *(const unsigned*)(featb + s0 * 128 + lane * 2);
            const unsigned ub = *(const unsigned*)(featb + s1 * 128 + lane * 2);
            s0 = (i + 2 < e) ? ssrc[i + 2] : 0;
            s1 = (i + 3 < e) ? ssrc[i + 3] : 0;
            a0 += bf_lo(ua) + bf_lo(ub);
            a1 += bf_hi(ua) + bf_hi(ub);
        }
        if (i < e) {
            const unsigned ua = *(const unsigned*)(featb + s0 * 128 + lane * 2);
            a0 += bf_lo(ua);
            a1 += bf_hi(ua);
        }
        const float inv = 1.0f / fmaxf((float)(e - b), 1.0f);
        At[row][lane * 2]     = a0 * inv;
        At[row][lane * 2 + 1] = a1 * inv;
        float r0 = 0.f, r1 = 0.f;
        if (n < NN) {
            if (ROOT_BF16) {
                const unsigned ur = *(const unsigned*)((const __hip_bfloat16*)rootp + n * 128 + lane * 2);
                r0 = bf_lo(ur); r1 = bf_hi(ur);
            } else {
                const float2 fr = *(const float2*)((const float*)rootp + n * 128 + lane * 2);
                r0 = fr.x; r1 = fr.y;
            }
        }
        At[row][128 + lane * 2]     = r0;
        At[row][128 + lane * 2 + 1] = r1;
    }
    __syncthreads();

    // GEMM phase (fp32): acc = At[:, 0:128] @ Wl + At[:, 128:256] @ Wr
    const int c = t & 31, r = t >> 5;
    float acc[4][4] = {};
#pragma unroll
    for (int h = 0; h < 2; ++h) {
        const float* __restrict__ W = h ? Wr : Wl;
        const int kb = h * 128;
        for (int k4 = 0; k4 < 128; k4 += 4) {
            float4 a[4];
#pragma unroll
            for (int u = 0; u < 4; ++u)
                a[u] = *(const float4*)&At[r + 8 * u][kb + k4];
#pragma unroll
            for (int kk = 0; kk < 4; ++kk) {
                float wv4[4];
#pragma unroll
                for (int v = 0; v < 4; ++v)
                    wv4[v] = W[(k4 + kk) * 128 + c + 32 * v];
#pragma unroll
                for (int u = 0; u < 4; ++u) {
                    const float av = reinterpret_cast<const float*>(&a[u])[kk];
#pragma unroll
                    for (int v = 0; v < 4; ++v)
                        acc[u][v] = fmaf(av, wv4[v], acc[u][v]);
                }
            }
        }
    }
#pragma unroll
    for (int v = 0; v < 4; ++v) {
        const int col = c + 32 * v;
        const float bv = bl[col];
#pragma unroll
        for (int u = 0; u < 4; ++u) {
            const int node = node0 + r + 8 * u;
            if (node < NN)
                outp[node * 128 + col] = __float2bfloat16(fmaxf(acc[u][v] + bv, 0.0f));
        }
    }
}

// ---------- PQ GEMM: pqb[n][0:256]=h2[n]@W3_top ; pqb[n][256:512]=h2[n]@W3_bot + b3 ----------
__global__ __launch_bounds__(256) void pq_gemm(const __hip_bfloat16* __restrict__ h2b,
                                               const __hip_bfloat16* __restrict__ wpq,
                                               const float* __restrict__ b3,
                                               __hip_bfloat16* __restrict__ pqb) {
    __shared__ __align__(16) char A[64 * 256];  // 64 rows x 128 bf16, XOR-swizzled
    const int t = threadIdx.x;
    const int n0 = blockIdx.x * 64;
    {
        const int row = t >> 2, part = t & 3;
        const int node = n0 + row;
        const int sw = (row & 7) << 4;
#pragma unroll
        for (int i = 0; i < 4; ++i) {
            const int inner = part * 64 + i * 16;
            uint4 v = make_uint4(0u, 0u, 0u, 0u);
            if (node < NN) v = *(const uint4*)((const char*)(h2b + node * 128) + inner);
            *(uint4*)(A + row * 256 + (inner ^ sw)) = v;
        }
    }
    __syncthreads();

    const int w = t >> 6, l = t & 63;
    const int lr = l & 15, lg = l >> 4;
    const int cb = w * 128;
    f32x4 acc[4][8] = {};
    for (int ks = 0; ks < 4; ++ks) {
        short8 af[4], bf[8];
        const int innerA = ks * 64 + lg * 16;
#pragma unroll
        for (int rt = 0; rt < 4; ++rt) {
            const int row = rt * 16 + lr;
            af[rt] = *(const short8*)(A + row * 256 + (innerA ^ ((row & 7) << 4)));
        }
        const int kidx = ks * 32 + lg * 8;
#pragma unroll
        for (int ct = 0; ct < 8; ++ct) {
            const int col = cb + ct * 16 + lr;
            bf[ct] = *(const short8*)(wpq + col * 128 + kidx);
        }
#pragma unroll
        for (int rt = 0; rt < 4; ++rt)
#pragma unroll
            for (int ct = 0; ct < 8; ++ct)
                acc[rt][ct] = __builtin_amdgcn_mfma_f32_16x16x32_bf16(af[rt], bf[ct], acc[rt][ct], 0, 0, 0);
    }
#pragma unroll
    for (int ct = 0; ct < 8; ++ct) {
        const int col = cb + ct * 16 + lr;
        const float badd = (col >= 256) ? b3[col - 256] : 0.f;
#pragma unroll
        for (int rt = 0; rt < 4; ++rt)
#pragma unroll
            for (int j = 0; j < 4; ++j) {
                const int node = n0 + rt * 16 + lg * 4 + j;
                if (node < NN)
                    pqb[(size_t)node * 512 + col] = __float2bfloat16(acc[rt][ct][j] + badd);
            }
    }
}

// ---------- edge: out[eid] = W4 . relu(P[src] + Q'[dst]) + b4, sorted-by-dst order ----------
__global__ __launch_bounds__(256) void edge_kernel(const int* __restrict__ ssrc,
                                                   const int* __restrict__ sdst,
                                                   const int* __restrict__ seid,
                                                   const __hip_bfloat16* __restrict__ pqb,
                                                   const float* __restrict__ W4,
                                                   const float* __restrict__ b4,
                                                   float* __restrict__ out) {
    const int i = threadIdx.x & 7;
    const int g = threadIdx.x >> 3;
    float w4r[4][8];
#pragma unroll
    for (int j = 0; j < 4; ++j)
#pragma unroll
        for (int u = 0; u < 8; ++u)
            w4r[j][u] = W4[i * 8 + j * 64 + u];
    const float b4v = b4[0];
    for (int p = blockIdx.x * 32 + g; p < NE; p += gridDim.x * 32) {
        const int s = ssrc[p], d = sdst[p], eid = seid[p];
        const char* Pp = (const char*)(pqb + (size_t)s * 512 + i * 8);
        const char* Qp = (const char*)(pqb + (size_t)d * 512 + 256 + i * 8);
        float acc = 0.f;
#pragma unroll
        for (int j = 0; j < 4; ++j) {
            const uint4 pv = *(const uint4*)(Pp + j * 128);
            const uint4 qv = *(const uint4*)(Qp + j * 128);
            const unsigned pa[4] = {pv.x, pv.y, pv.z, pv.w};
            const unsigned qa[4] = {qv.x, qv.y, qv.z, qv.w};
#pragma unroll
            for (int q4 = 0; q4 < 4; ++q4) {
                const float hlo = fmaxf(bf_lo(pa[q4]) + bf_lo(qa[q4]), 0.f);
                const float hhi = fmaxf(bf_hi(pa[q4]) + bf_hi(qa[q4]), 0.f);
                acc = fmaf(hlo, w4r[j][q4 * 2], acc);
                acc = fmaf(hhi, w4r[j][q4 * 2 + 1], acc);
            }
        }
        acc += __shfl_xor(acc, 1);
        acc += __shfl_xor(acc, 2);
        acc += __shfl_xor(acc, 4);
        if (i == 0) out[eid] = acc + b4v;
    }
}

extern "C" void kernel_launch(void* const* d_in, const int* in_sizes, int n_in,
                              void* d_out, int out_size, void* d_ws, size_t ws_size,
                              hipStream_t stream) {
    const float* x   = (const float*)d_in[0];
    const int* ei    = (const int*)d_in[1];
    const float* W1l = (const float*)d_in[2];
    const float* b1l = (const float*)d_in[3];
    const float* W1r = (const float*)d_in[4];
    const float* W2l = (const float*)d_in[5];
    const float* b2l = (const float*)d_in[6];
    const float* W2r = (const float*)d_in[7];
    const float* W3  = (const float*)d_in[8];
    const float* b3  = (const float*)d_in[9];
    const float* W4  = (const float*)d_in[10];
    const float* b4  = (const float*)d_in[11];
    float* out = (float*)d_out;

    char* ws = (char*)d_ws;
    int* cnt            = (int*)(ws);                        // 200 KB
    int* off            = (int*)(ws + 200704);
    int* cursor         = (int*)(ws + 401408);
    int* ssrc           = (int*)(ws + 602112);               // 3.2 MB
    int* sdst           = (int*)(ws + 3802112);              // 3.2 MB
    int* seid           = (int*)(ws + 7002112);              // 3.2 MB
    __hip_bfloat16* xb  = (__hip_bfloat16*)(ws + 10202112);  // 12.8 MB
    __hip_bfloat16* h1b = (__hip_bfloat16*)(ws + 23002112);  // 12.8 MB
    int* bsum           = (int*)(ws + 35802112);             // small
    __hip_bfloat16* h2b = (__hip_bfloat16*)(ws + 61402112);  // 12.8 MB
    __hip_bfloat16* pqb = (__hip_bfloat16*)(ws + 10202112);  // 51.2 MB, overlays xb+h1b
    __hip_bfloat16* wpq = (__hip_bfloat16*)(ws + 74202112);  // 128 KB

    hipMemsetAsync(cnt, 0, NN * sizeof(int), stream);
    hist_kernel<<<1024, 256, 0, stream>>>(ei, cnt);
    scan_blk<<<SCAN_G, 256, 0, stream>>>(cnt, off, bsum);
    scan_top<<<1, 256, 0, stream>>>(bsum);
    scan_add<<<SCAN_G, 256, 0, stream>>>(off, cursor, bsum);
    fill_kernel<<<1024, 256, 0, stream>>>(ei, cursor, ssrc, sdst, seid);
    prep_wpq<<<64, 256, 0, stream>>>(W3, wpq);
    prep_xb<<<(NN * 128 / 4 + 255) / 256, 256, 0, stream>>>(x, xb);

    fused_conv<false><<<(NN + 31) / 32, 256, 0, stream>>>(xb, off, ssrc, (const void*)x, W1l, W1r, b1l, h1b);
    fused_conv<true><<<(NN + 31) / 32, 256, 0, stream>>>(h1b, off, ssrc, (const void*)h1b, W2l, W2r, b2l, h2b);
    pq_gemm<<<(NN + 63) / 64, 256, 0, stream>>>(h2b, wpq, b3, pqb);
    edge_kernel<<<2048, 256, 0, stream>>>(ssrc, sdst, seid, pqb, W4, b4, out);
}

// Round 6
// 445.336 us; speedup vs baseline: 2.7487x; 1.3368x over previous
//
#include <hip/hip_runtime.h>
#include <hip/hip_bf16.h>

#define NN 50000
#define NE 800000
#define SCAN_G ((NN + 255) / 256)  // 196

typedef __attribute__((ext_vector_type(8))) short short8;
typedef __attribute__((ext_vector_type(4))) float f32x4;

__device__ inline float bf_lo(unsigned u) { u <<= 16; float f; __builtin_memcpy(&f, &u, 4); return f; }
__device__ inline float bf_hi(unsigned u) { u &= 0xffff0000u; float f; __builtin_memcpy(&f, &u, 4); return f; }
__device__ inline unsigned pack_bf16x2(float a, float b) {
    __hip_bfloat16 ba = __float2bfloat16(a), bb = __float2bfloat16(b);
    unsigned short ua, ub;
    __builtin_memcpy(&ua, &ba, 2);
    __builtin_memcpy(&ub, &bb, 2);
    return (unsigned)ua | ((unsigned)ub << 16);
}

// ---------- prep: wpq bf16 [512 outcols][128 k] for the edge-MLP PQ GEMM ----------
__global__ void prep_wpq(const float* __restrict__ W3, __hip_bfloat16* __restrict__ wpq) {
    const int idx4 = (blockIdx.x * 256 + threadIdx.x) * 4;
    const int c = idx4 >> 7;
    const int k0 = idx4 & 127;
#pragma unroll
    for (int i = 0; i < 4; ++i) {
        const int k = k0 + i;
        const float v = (c < 256) ? W3[k * 256 + c] : W3[(128 + k) * 256 + (c - 256)];
        wpq[c * 128 + k] = __float2bfloat16(v);
    }
}

// ---------- prep: conv weights bf16 w12t[layer][256 col][128 k]; col<128 -> Wl, else Wr ----------
__global__ void prep_w12t(const float* __restrict__ W1l, const float* __restrict__ W1r,
                          const float* __restrict__ W2l, const float* __restrict__ W2r,
                          __hip_bfloat16* __restrict__ w12t) {
    const int idx = blockIdx.x * 256 + threadIdx.x;  // 65536 total
    const int layer = idx >> 15;
    const int c = (idx >> 7) & 255;
    const int k = idx & 127;
    const float* W = layer ? (c < 128 ? W2l : W2r) : (c < 128 ? W1l : W1r);
    w12t[idx] = __float2bfloat16(W[k * 128 + (c & 127)]);
}

// ---------- CSR build ----------
__global__ __launch_bounds__(256) void hist_kernel(const int* __restrict__ ei,
                                                   int* __restrict__ cnt) {
    for (int e = blockIdx.x * 256 + threadIdx.x; e < NE; e += gridDim.x * 256)
        atomicAdd(&cnt[ei[NE + e]], 1);
}

__global__ __launch_bounds__(256) void scan_blk(const int* __restrict__ cnt,
                                                int* __restrict__ off,
                                                int* __restrict__ bsum) {
    __shared__ int sm[256];
    const int t = threadIdx.x;
    const int i = blockIdx.x * 256 + t;
    const int v = (i < NN) ? cnt[i] : 0;
    sm[t] = v;
    __syncthreads();
    for (int d = 1; d < 256; d <<= 1) {
        const int add = (t >= d) ? sm[t - d] : 0;
        __syncthreads();
        sm[t] += add;
        __syncthreads();
    }
    if (i < NN) off[i] = sm[t] - v;
    if (t == 255) bsum[blockIdx.x] = sm[255];
}

__global__ __launch_bounds__(256) void scan_top(int* __restrict__ bsum) {
    __shared__ int sm[256];
    const int t = threadIdx.x;
    const int v = (t < SCAN_G) ? bsum[t] : 0;
    sm[t] = v;
    __syncthreads();
    for (int d = 1; d < 256; d <<= 1) {
        const int add = (t >= d) ? sm[t - d] : 0;
        __syncthreads();
        sm[t] += add;
        __syncthreads();
    }
    if (t < SCAN_G) bsum[t] = sm[t] - v;
}

__global__ __launch_bounds__(256) void scan_add(int* __restrict__ off,
                                                int* __restrict__ cursor,
                                                const int* __restrict__ bsum) {
    const int t = threadIdx.x;
    const int i = blockIdx.x * 256 + t;
    if (i < NN) {
        const int v = off[i] + bsum[blockIdx.x];
        off[i] = v;
        cursor[i] = v;
    }
    if (i == NN - 1) off[NN] = NE;
}

__global__ __launch_bounds__(256) void fill_kernel(const int* __restrict__ ei,
                                                   int* __restrict__ cursor,
                                                   int* __restrict__ ssrc,
                                                   int* __restrict__ sdst,
                                                   int* __restrict__ seid) {
    for (int e = blockIdx.x * 256 + threadIdx.x; e < NE; e += gridDim.x * 256) {
        const int d = ei[NE + e];
        const int p = atomicAdd(&cursor[d], 1);
        ssrc[p] = ei[e];
        sdst[p] = d;
        seid[p] = e;
    }
}

// ---------- projection GEMM: ob[n][0:128]=in[n]@Wl (y), ob[n][128:256]=in[n]@Wr (z) ----------
// IN_F32: input is fp32 [NN,128] (layer1, x); else bf16 [NN,128] (layer2, h1b).
template <bool IN_F32>
__global__ __launch_bounds__(256) void proj_gemm(const void* __restrict__ inp,
                                                 const __hip_bfloat16* __restrict__ wt,
                                                 __hip_bfloat16* __restrict__ ob) {
    __shared__ __align__(16) char A[64 * 256];  // 64 rows x 128 bf16, XOR-swizzled
    const int t = threadIdx.x;
    const int n0 = blockIdx.x * 64;
    {
        const int row = t >> 2, part = t & 3;
        const int node = n0 + row;
        const int sw = (row & 7) << 4;
        if (IN_F32) {
            const float* xp = (const float*)inp + (size_t)node * 128 + part * 32;
#pragma unroll
            for (int i = 0; i < 8; ++i) {
                uint2 w = make_uint2(0u, 0u);
                if (node < NN) {
                    const float4 v = *(const float4*)(xp + i * 4);
                    w.x = pack_bf16x2(v.x, v.y);
                    w.y = pack_bf16x2(v.z, v.w);
                }
                const int inner = part * 64 + i * 8;
                *(uint2*)(A + row * 256 + (inner ^ sw)) = w;
            }
        } else {
            const char* srcp = (const char*)((const __hip_bfloat16*)inp + (size_t)node * 128);
#pragma unroll
            for (int i = 0; i < 4; ++i) {
                const int inner = part * 64 + i * 16;
                uint4 v = make_uint4(0u, 0u, 0u, 0u);
                if (node < NN) v = *(const uint4*)(srcp + inner);
                *(uint4*)(A + row * 256 + (inner ^ sw)) = v;
            }
        }
    }
    __syncthreads();

    const int w = t >> 6, l = t & 63;
    const int lr = l & 15, lg = l >> 4;
    const int cb = w * 64;  // 4 waves x 64 cols = 256
    f32x4 acc[4][4] = {};
    for (int ks = 0; ks < 4; ++ks) {
        short8 af[4], bf[4];
        const int innerA = ks * 64 + lg * 16;
#pragma unroll
        for (int rt = 0; rt < 4; ++rt) {
            const int row = rt * 16 + lr;
            af[rt] = *(const short8*)(A + row * 256 + (innerA ^ ((row & 7) << 4)));
        }
        const int kidx = ks * 32 + lg * 8;
#pragma unroll
        for (int ct = 0; ct < 4; ++ct) {
            const int col = cb + ct * 16 + lr;
            bf[ct] = *(const short8*)(wt + col * 128 + kidx);
        }
#pragma unroll
        for (int rt = 0; rt < 4; ++rt)
#pragma unroll
            for (int ct = 0; ct < 4; ++ct)
                acc[rt][ct] = __builtin_amdgcn_mfma_f32_16x16x32_bf16(af[rt], bf[ct], acc[rt][ct], 0, 0, 0);
    }
#pragma unroll
    for (int ct = 0; ct < 4; ++ct) {
        const int col = cb + ct * 16 + lr;
#pragma unroll
        for (int rt = 0; rt < 4; ++rt)
#pragma unroll
            for (int j = 0; j < 4; ++j) {
                const int node = n0 + rt * 16 + lg * 4 + j;
                if (node < NN)
                    ob[(size_t)node * 256 + col] = __float2bfloat16(acc[rt][ct][j]);
            }
    }
}

// ---------- gather-mean + bias + relu: h[n] = bf16(relu(mean_s y[s] + z[n] + b)) ----------
__global__ __launch_bounds__(256) void gather_fuse(const __hip_bfloat16* __restrict__ ob,
                                                   const int* __restrict__ off,
                                                   const int* __restrict__ ssrc,
                                                   const float* __restrict__ bl,
                                                   __hip_bfloat16* __restrict__ outp) {
    const int wv = threadIdx.x >> 6, lane = threadIdx.x & 63;
    const float2 bv = *(const float2*)&bl[lane * 2];
    for (int n = blockIdx.x * 4 + wv; n < NN; n += gridDim.x * 4) {
        const int b = off[n], e = off[n + 1];
        float a0 = 0.f, a1 = 0.f;
        int i = b;
        int s0 = (i + 0 < e) ? ssrc[i + 0] : 0;
        int s1 = (i + 1 < e) ? ssrc[i + 1] : 0;
        int s2 = (i + 2 < e) ? ssrc[i + 2] : 0;
        int s3 = (i + 3 < e) ? ssrc[i + 3] : 0;
        for (; i + 4 <= e;) {
            const unsigned u0 = *(const unsigned*)(ob + (size_t)s0 * 256 + lane * 2);
            const unsigned u1 = *(const unsigned*)(ob + (size_t)s1 * 256 + lane * 2);
            const unsigned u2 = *(const unsigned*)(ob + (size_t)s2 * 256 + lane * 2);
            const unsigned u3 = *(const unsigned*)(ob + (size_t)s3 * 256 + lane * 2);
            i += 4;
            s0 = (i + 0 < e) ? ssrc[i + 0] : 0;
            s1 = (i + 1 < e) ? ssrc[i + 1] : 0;
            s2 = (i + 2 < e) ? ssrc[i + 2] : 0;
            s3 = (i + 3 < e) ? ssrc[i + 3] : 0;
            a0 += bf_lo(u0) + bf_lo(u1) + bf_lo(u2) + bf_lo(u3);
            a1 += bf_hi(u0) + bf_hi(u1) + bf_hi(u2) + bf_hi(u3);
        }
        if (i < e) {
            const unsigned u = *(const unsigned*)(ob + (size_t)s0 * 256 + lane * 2);
            a0 += bf_lo(u); a1 += bf_hi(u); ++i;
            if (i < e) {
                const unsigned u1_ = *(const unsigned*)(ob + (size_t)s1 * 256 + lane * 2);
                a0 += bf_lo(u1_); a1 += bf_hi(u1_); ++i;
                if (i < e) {
                    const unsigned u2_ = *(const unsigned*)(ob + (size_t)s2 * 256 + lane * 2);
                    a0 += bf_lo(u2_); a1 += bf_hi(u2_);
                }
            }
        }
        const float inv = 1.0f / fmaxf((float)(e - b), 1.0f);
        const unsigned uz = *(const unsigned*)(ob + (size_t)n * 256 + 128 + lane * 2);
        const float h0 = fmaxf(a0 * inv + bf_lo(uz) + bv.x, 0.0f);
        const float h1 = fmaxf(a1 * inv + bf_hi(uz) + bv.y, 0.0f);
        *(unsigned*)((char*)outp + (size_t)n * 256 + lane * 4) = pack_bf16x2(h0, h1);
    }
}

// ---------- PQ GEMM: pqb[n][0:256]=h2[n]@W3_top ; pqb[n][256:512]=h2[n]@W3_bot + b3 ----------
__global__ __launch_bounds__(256) void pq_gemm(const __hip_bfloat16* __restrict__ h2b,
                                               const __hip_bfloat16* __restrict__ wpq,
                                               const float* __restrict__ b3,
                                               __hip_bfloat16* __restrict__ pqb) {
    __shared__ __align__(16) char A[64 * 256];
    const int t = threadIdx.x;
    const int n0 = blockIdx.x * 64;
    {
        const int row = t >> 2, part = t & 3;
        const int node = n0 + row;
        const int sw = (row & 7) << 4;
#pragma unroll
        for (int i = 0; i < 4; ++i) {
            const int inner = part * 64 + i * 16;
            uint4 v = make_uint4(0u, 0u, 0u, 0u);
            if (node < NN) v = *(const uint4*)((const char*)(h2b + node * 128) + inner);
            *(uint4*)(A + row * 256 + (inner ^ sw)) = v;
        }
    }
    __syncthreads();

    const int w = t >> 6, l = t & 63;
    const int lr = l & 15, lg = l >> 4;
    const int cb = w * 128;
    f32x4 acc[4][8] = {};
    for (int ks = 0; ks < 4; ++ks) {
        short8 af[4], bf[8];
        const int innerA = ks * 64 + lg * 16;
#pragma unroll
        for (int rt = 0; rt < 4; ++rt) {
            const int row = rt * 16 + lr;
            af[rt] = *(const short8*)(A + row * 256 + (innerA ^ ((row & 7) << 4)));
        }
        const int kidx = ks * 32 + lg * 8;
#pragma unroll
        for (int ct = 0; ct < 8; ++ct) {
            const int col = cb + ct * 16 + lr;
            bf[ct] = *(const short8*)(wpq + col * 128 + kidx);
        }
#pragma unroll
        for (int rt = 0; rt < 4; ++rt)
#pragma unroll
            for (int ct = 0; ct < 8; ++ct)
                acc[rt][ct] = __builtin_amdgcn_mfma_f32_16x16x32_bf16(af[rt], bf[ct], acc[rt][ct], 0, 0, 0);
    }
#pragma unroll
    for (int ct = 0; ct < 8; ++ct) {
        const int col = cb + ct * 16 + lr;
        const float badd = (col >= 256) ? b3[col - 256] : 0.f;
#pragma unroll
        for (int rt = 0; rt < 4; ++rt)
#pragma unroll
            for (int j = 0; j < 4; ++j) {
                const int node = n0 + rt * 16 + lg * 4 + j;
                if (node < NN)
                    pqb[(size_t)node * 512 + col] = __float2bfloat16(acc[rt][ct][j] + badd);
            }
    }
}

// ---------- edge: out[eid] = W4 . relu(P[src] + Q'[dst]) + b4, sorted-by-dst order ----------
__global__ __launch_bounds__(256) void edge_kernel(const int* __restrict__ ssrc,
                                                   const int* __restrict__ sdst,
                                                   const int* __restrict__ seid,
                                                   const __hip_bfloat16* __restrict__ pqb,
                                                   const float* __restrict__ W4,
                                                   const float* __restrict__ b4,
                                                   float* __restrict__ out) {
    const int i = threadIdx.x & 7;
    const int g = threadIdx.x >> 3;
    float w4r[4][8];
#pragma unroll
    for (int j = 0; j < 4; ++j)
#pragma unroll
        for (int u = 0; u < 8; ++u)
            w4r[j][u] = W4[i * 8 + j * 64 + u];
    const float b4v = b4[0];
    for (int p = blockIdx.x * 32 + g; p < NE; p += gridDim.x * 32) {
        const int s = ssrc[p], d = sdst[p], eid = seid[p];
        const char* Pp = (const char*)(pqb + (size_t)s * 512 + i * 8);
        const char* Qp = (const char*)(pqb + (size_t)d * 512 + 256 + i * 8);
        float acc = 0.f;
#pragma unroll
        for (int j = 0; j < 4; ++j) {
            const uint4 pv = *(const uint4*)(Pp + j * 128);
            const uint4 qv = *(const uint4*)(Qp + j * 128);
            const unsigned pa[4] = {pv.x, pv.y, pv.z, pv.w};
            const unsigned qa[4] = {qv.x, qv.y, qv.z, qv.w};
#pragma unroll
            for (int q4 = 0; q4 < 4; ++q4) {
                const float hlo = fmaxf(bf_lo(pa[q4]) + bf_lo(qa[q4]), 0.f);
                const float hhi = fmaxf(bf_hi(pa[q4]) + bf_hi(qa[q4]), 0.f);
                acc = fmaf(hlo, w4r[j][q4 * 2], acc);
                acc = fmaf(hhi, w4r[j][q4 * 2 + 1], acc);
            }
        }
        acc += __shfl_xor(acc, 1);
        acc += __shfl_xor(acc, 2);
        acc += __shfl_xor(acc, 4);
        if (i == 0) out[eid] = acc + b4v;
    }
}

extern "C" void kernel_launch(void* const* d_in, const int* in_sizes, int n_in,
                              void* d_out, int out_size, void* d_ws, size_t ws_size,
                              hipStream_t stream) {
    const float* x   = (const float*)d_in[0];
    const int* ei    = (const int*)d_in[1];
    const float* W1l = (const float*)d_in[2];
    const float* b1l = (const float*)d_in[3];
    const float* W1r = (const float*)d_in[4];
    const float* W2l = (const float*)d_in[5];
    const float* b2l = (const float*)d_in[6];
    const float* W2r = (const float*)d_in[7];
    const float* W3  = (const float*)d_in[8];
    const float* b3  = (const float*)d_in[9];
    const float* W4  = (const float*)d_in[10];
    const float* b4  = (const float*)d_in[11];
    float* out = (float*)d_out;

    char* ws = (char*)d_ws;
    int* cnt            = (int*)(ws);                        // 200 KB
    int* off            = (int*)(ws + 200704);
    int* cursor         = (int*)(ws + 401408);
    int* ssrc           = (int*)(ws + 602112);               // 3.2 MB
    int* sdst           = (int*)(ws + 3802112);              // 3.2 MB
    int* seid           = (int*)(ws + 7002112);              // 3.2 MB
    __hip_bfloat16* pqb = (__hip_bfloat16*)(ws + 10202112);  // 51.2 MB (overlays h1b+ob)
    __hip_bfloat16* h1b = (__hip_bfloat16*)(ws + 23002112);  // 12.8 MB (dead before pq_gemm)
    __hip_bfloat16* ob  = (__hip_bfloat16*)(ws + 35802112);  // 25.6 MB (dead before pq_gemm)
    __hip_bfloat16* h2b = (__hip_bfloat16*)(ws + 61402112);  // 12.8 MB
    __hip_bfloat16* wpq = (__hip_bfloat16*)(ws + 74202112);  // 128 KB
    __hip_bfloat16* w12t= (__hip_bfloat16*)(ws + 74333184);  // 128 KB

    hipMemsetAsync(cnt, 0, NN * sizeof(int), stream);
    hist_kernel<<<1024, 256, 0, stream>>>(ei, cnt);
    scan_blk<<<SCAN_G, 256, 0, stream>>>(cnt, off, cursor + NN);  // bsum scratch: reuse tail? no—
    // NOTE: bsum needs SCAN_G ints; use a dedicated spot in cnt region after scan (cnt dead after scan_blk reads it)
    scan_top<<<1, 256, 0, stream>>>(cursor + NN);
    scan_add<<<SCAN_G, 256, 0, stream>>>(off, cursor, cursor + NN);
    fill_kernel<<<1024, 256, 0, stream>>>(ei, cursor, ssrc, sdst, seid);
    prep_wpq<<<64, 256, 0, stream>>>(W3, wpq);
    prep_w12t<<<256, 256, 0, stream>>>(W1l, W1r, W2l, W2r, w12t);

    proj_gemm<true><<<(NN + 63) / 64, 256, 0, stream>>>((const void*)x, w12t, ob);
    gather_fuse<<<2048, 256, 0, stream>>>(ob, off, ssrc, b1l, h1b);
    proj_gemm<false><<<(NN + 63) / 64, 256, 0, stream>>>((const void*)h1b, w12t + 256 * 128, ob);
    gather_fuse<<<2048, 256, 0, stream>>>(ob, off, ssrc, b2l, h2b);
    pq_gemm<<<(NN + 63) / 64, 256, 0, stream>>>(h2b, wpq, b3, pqb);
    edge_kernel<<<2048, 256, 0, stream>>>(ssrc, sdst, seid, pqb, W4, b4, out);
}

// Round 7
// 394.306 us; speedup vs baseline: 3.1045x; 1.1294x over previous
//
#include <hip/hip_runtime.h>
#include <hip/hip_bf16.h>

#define NN 50000
#define NE 800000
#define SCAN_G ((NN + 255) / 256)  // 196

typedef __attribute__((ext_vector_type(8))) short short8;
typedef __attribute__((ext_vector_type(4))) float f32x4;

__device__ inline float bf_lo(unsigned u) { u <<= 16; float f; __builtin_memcpy(&f, &u, 4); return f; }
__device__ inline float bf_hi(unsigned u) { u &= 0xffff0000u; float f; __builtin_memcpy(&f, &u, 4); return f; }
__device__ inline unsigned pack_bf16x2(float a, float b) {
    __hip_bfloat16 ba = __float2bfloat16(a), bb = __float2bfloat16(b);
    unsigned short ua, ub;
    __builtin_memcpy(&ua, &ba, 2);
    __builtin_memcpy(&ub, &bb, 2);
    return (unsigned)ua | ((unsigned)ub << 16);
}
__device__ inline __hip_bfloat16 f2bf(float a) { return __float2bfloat16(a); }

// ---------- prep: wpq bf16 [512 outcols][128 k] for the edge-MLP PQ GEMM ----------
__global__ void prep_wpq(const float* __restrict__ W3, __hip_bfloat16* __restrict__ wpq) {
    const int idx4 = (blockIdx.x * 256 + threadIdx.x) * 4;
    const int c = idx4 >> 7;
    const int k0 = idx4 & 127;
#pragma unroll
    for (int i = 0; i < 4; ++i) {
        const int k = k0 + i;
        const float v = (c < 256) ? W3[k * 256 + c] : W3[(128 + k) * 256 + (c - 256)];
        wpq[c * 128 + k] = __float2bfloat16(v);
    }
}

// ---------- prep: conv weights bf16 w12t[layer][256 col][128 k]; col<128 -> Wl, else Wr ----------
__global__ void prep_w12t(const float* __restrict__ W1l, const float* __restrict__ W1r,
                          const float* __restrict__ W2l, const float* __restrict__ W2r,
                          __hip_bfloat16* __restrict__ w12t) {
    const int idx = blockIdx.x * 256 + threadIdx.x;  // 65536 total
    const int layer = idx >> 15;
    const int c = (idx >> 7) & 255;
    const int k = idx & 127;
    const float* W = layer ? (c < 128 ? W2l : W2r) : (c < 128 ? W1l : W1r);
    w12t[idx] = __float2bfloat16(W[k * 128 + (c & 127)]);
}

// ---------- CSR build ----------
__global__ __launch_bounds__(256) void hist_kernel(const int* __restrict__ ei,
                                                   int* __restrict__ cnt) {
    for (int e = blockIdx.x * 256 + threadIdx.x; e < NE; e += gridDim.x * 256)
        atomicAdd(&cnt[ei[NE + e]], 1);
}

__global__ __launch_bounds__(256) void scan_blk(const int* __restrict__ cnt,
                                                int* __restrict__ off,
                                                int* __restrict__ bsum) {
    __shared__ int sm[256];
    const int t = threadIdx.x;
    const int i = blockIdx.x * 256 + t;
    const int v = (i < NN) ? cnt[i] : 0;
    sm[t] = v;
    __syncthreads();
    for (int d = 1; d < 256; d <<= 1) {
        const int add = (t >= d) ? sm[t - d] : 0;
        __syncthreads();
        sm[t] += add;
        __syncthreads();
    }
    if (i < NN) off[i] = sm[t] - v;
    if (t == 255) bsum[blockIdx.x] = sm[255];
}

__global__ __launch_bounds__(256) void scan_top(int* __restrict__ bsum) {
    __shared__ int sm[256];
    const int t = threadIdx.x;
    const int v = (t < SCAN_G) ? bsum[t] : 0;
    sm[t] = v;
    __syncthreads();
    for (int d = 1; d < 256; d <<= 1) {
        const int add = (t >= d) ? sm[t - d] : 0;
        __syncthreads();
        sm[t] += add;
        __syncthreads();
    }
    if (t < SCAN_G) bsum[t] = sm[t] - v;
}

__global__ __launch_bounds__(256) void scan_add(int* __restrict__ off,
                                                int* __restrict__ cursor,
                                                const int* __restrict__ bsum) {
    const int t = threadIdx.x;
    const int i = blockIdx.x * 256 + t;
    if (i < NN) {
        const int v = off[i] + bsum[blockIdx.x];
        off[i] = v;
        cursor[i] = v;
    }
    if (i == NN - 1) off[NN] = NE;
}

__global__ __launch_bounds__(256) void fill_kernel(const int* __restrict__ ei,
                                                   int* __restrict__ cursor,
                                                   int* __restrict__ ssrc,
                                                   int* __restrict__ sdst,
                                                   int* __restrict__ seid) {
    for (int e = blockIdx.x * 256 + threadIdx.x; e < NE; e += gridDim.x * 256) {
        const int d = ei[NE + e];
        const int p = atomicAdd(&cursor[d], 1);
        ssrc[p] = ei[e];
        sdst[p] = d;
        seid[p] = e;
    }
}

// ---------- projection GEMM: ob[n][0:128]=in[n]@Wl (y), ob[n][128:256]=in[n]@Wr (z) ----------
template <bool IN_F32>
__global__ __launch_bounds__(256) void proj_gemm(const void* __restrict__ inp,
                                                 const __hip_bfloat16* __restrict__ wt,
                                                 __hip_bfloat16* __restrict__ ob) {
    __shared__ __align__(16) char A[16384];  // A-tiles (64x256B), reused for C-chunks (16x528B)
    const int t = threadIdx.x;
    const int n0 = blockIdx.x * 64;
    {
        const int row = t >> 2, part = t & 3;
        const int node = n0 + row;
        const int sw = (row & 7) << 4;
        if (IN_F32) {
            const float* xp = (const float*)inp + (size_t)node * 128 + part * 32;
#pragma unroll
            for (int i = 0; i < 8; ++i) {
                uint2 w = make_uint2(0u, 0u);
                if (node < NN) {
                    const float4 v = *(const float4*)(xp + i * 4);
                    w.x = pack_bf16x2(v.x, v.y);
                    w.y = pack_bf16x2(v.z, v.w);
                }
                const int inner = part * 64 + i * 8;
                *(uint2*)(A + row * 256 + (inner ^ sw)) = w;
            }
        } else {
            const char* srcp = (const char*)((const __hip_bfloat16*)inp + (size_t)node * 128);
#pragma unroll
            for (int i = 0; i < 4; ++i) {
                const int inner = part * 64 + i * 16;
                uint4 v = make_uint4(0u, 0u, 0u, 0u);
                if (node < NN) v = *(const uint4*)(srcp + inner);
                *(uint4*)(A + row * 256 + (inner ^ sw)) = v;
            }
        }
    }
    __syncthreads();

    const int w = t >> 6, l = t & 63;
    const int lr = l & 15, lg = l >> 4;
    const int cb = w * 64;  // 4 waves x 64 cols = 256
    f32x4 acc[4][4] = {};
    for (int ks = 0; ks < 4; ++ks) {
        short8 af[4], bf[4];
        const int innerA = ks * 64 + lg * 16;
#pragma unroll
        for (int rt = 0; rt < 4; ++rt) {
            const int row = rt * 16 + lr;
            af[rt] = *(const short8*)(A + row * 256 + (innerA ^ ((row & 7) << 4)));
        }
        const int kidx = ks * 32 + lg * 8;
#pragma unroll
        for (int ct = 0; ct < 4; ++ct) {
            const int col = cb + ct * 16 + lr;
            bf[ct] = *(const short8*)(wt + col * 128 + kidx);
        }
#pragma unroll
        for (int rt = 0; rt < 4; ++rt)
#pragma unroll
            for (int ct = 0; ct < 4; ++ct)
                acc[rt][ct] = __builtin_amdgcn_mfma_f32_16x16x32_bf16(af[rt], bf[ct], acc[rt][ct], 0, 0, 0);
    }
    // epilogue: LDS-staged coalesced stores (16-row chunks, stride 528B)
#pragma unroll
    for (int rt = 0; rt < 4; ++rt) {
        __syncthreads();
#pragma unroll
        for (int ct = 0; ct < 4; ++ct) {
            const int col = cb + ct * 16 + lr;
#pragma unroll
            for (int j = 0; j < 4; ++j) {
                const int row = lg * 4 + j;
                *(__hip_bfloat16*)(A + row * 528 + col * 2) = f2bf(acc[rt][ct][j]);
            }
        }
        __syncthreads();
        const int row = t >> 4, cc = t & 15;
        const int node = n0 + rt * 16 + row;
        if (node < NN) {
#pragma unroll
            for (int pass = 0; pass < 2; ++pass) {
                const int byteoff = pass * 256 + cc * 16;
                *(uint4*)((char*)(ob + (size_t)node * 256) + byteoff) =
                    *(const uint4*)(A + row * 528 + byteoff);
            }
        }
    }
}

// ---------- gather-mean + bias + relu: h[n] = bf16(relu(mean_s y[s] + z[n] + b)) ----------
__global__ __launch_bounds__(256) void gather_fuse(const __hip_bfloat16* __restrict__ ob,
                                                   const int* __restrict__ off,
                                                   const int* __restrict__ ssrc,
                                                   const float* __restrict__ bl,
                                                   __hip_bfloat16* __restrict__ outp) {
    const int wv = threadIdx.x >> 6, lane = threadIdx.x & 63;
    const float2 bv = *(const float2*)&bl[lane * 2];
    for (int n = blockIdx.x * 4 + wv; n < NN; n += gridDim.x * 4) {
        const int b = off[n], e = off[n + 1];
        float a0 = 0.f, a1 = 0.f;
        int i = b;
        int s0 = (i + 0 < e) ? ssrc[i + 0] : 0;
        int s1 = (i + 1 < e) ? ssrc[i + 1] : 0;
        int s2 = (i + 2 < e) ? ssrc[i + 2] : 0;
        int s3 = (i + 3 < e) ? ssrc[i + 3] : 0;
        for (; i + 4 <= e;) {
            const unsigned u0 = *(const unsigned*)(ob + (size_t)s0 * 256 + lane * 2);
            const unsigned u1 = *(const unsigned*)(ob + (size_t)s1 * 256 + lane * 2);
            const unsigned u2 = *(const unsigned*)(ob + (size_t)s2 * 256 + lane * 2);
            const unsigned u3 = *(const unsigned*)(ob + (size_t)s3 * 256 + lane * 2);
            i += 4;
            s0 = (i + 0 < e) ? ssrc[i + 0] : 0;
            s1 = (i + 1 < e) ? ssrc[i + 1] : 0;
            s2 = (i + 2 < e) ? ssrc[i + 2] : 0;
            s3 = (i + 3 < e) ? ssrc[i + 3] : 0;
            a0 += bf_lo(u0) + bf_lo(u1) + bf_lo(u2) + bf_lo(u3);
            a1 += bf_hi(u0) + bf_hi(u1) + bf_hi(u2) + bf_hi(u3);
        }
        if (i < e) {
            const unsigned u = *(const unsigned*)(ob + (size_t)s0 * 256 + lane * 2);
            a0 += bf_lo(u); a1 += bf_hi(u); ++i;
            if (i < e) {
                const unsigned u1_ = *(const unsigned*)(ob + (size_t)s1 * 256 + lane * 2);
                a0 += bf_lo(u1_); a1 += bf_hi(u1_); ++i;
                if (i < e) {
                    const unsigned u2_ = *(const unsigned*)(ob + (size_t)s2 * 256 + lane * 2);
                    a0 += bf_lo(u2_); a1 += bf_hi(u2_);
                }
            }
        }
        const float inv = 1.0f / fmaxf((float)(e - b), 1.0f);
        const unsigned uz = *(const unsigned*)(ob + (size_t)n * 256 + 128 + lane * 2);
        const float h0 = fmaxf(a0 * inv + bf_lo(uz) + bv.x, 0.0f);
        const float h1 = fmaxf(a1 * inv + bf_hi(uz) + bv.y, 0.0f);
        *(unsigned*)((char*)outp + (size_t)n * 256 + lane * 4) = pack_bf16x2(h0, h1);
    }
}

// ---------- PQ GEMM: pqb[n][0:256]=h2[n]@W3_top ; pqb[n][256:512]=h2[n]@W3_bot + b3 ----------
__global__ __launch_bounds__(256) void pq_gemm(const __hip_bfloat16* __restrict__ h2b,
                                               const __hip_bfloat16* __restrict__ wpq,
                                               const float* __restrict__ b3,
                                               __hip_bfloat16* __restrict__ pqb) {
    __shared__ __align__(16) char A[16640];  // A-tiles (64x256B), reused for C-chunks (16x1040B)
    const int t = threadIdx.x;
    const int n0 = blockIdx.x * 64;
    {
        const int row = t >> 2, part = t & 3;
        const int node = n0 + row;
        const int sw = (row & 7) << 4;
#pragma unroll
        for (int i = 0; i < 4; ++i) {
            const int inner = part * 64 + i * 16;
            uint4 v = make_uint4(0u, 0u, 0u, 0u);
            if (node < NN) v = *(const uint4*)((const char*)(h2b + node * 128) + inner);
            *(uint4*)(A + row * 256 + (inner ^ sw)) = v;
        }
    }
    __syncthreads();

    const int w = t >> 6, l = t & 63;
    const int lr = l & 15, lg = l >> 4;
    const int cb = w * 128;
    f32x4 acc[4][8] = {};
    for (int ks = 0; ks < 4; ++ks) {
        short8 af[4], bf[8];
        const int innerA = ks * 64 + lg * 16;
#pragma unroll
        for (int rt = 0; rt < 4; ++rt) {
            const int row = rt * 16 + lr;
            af[rt] = *(const short8*)(A + row * 256 + (innerA ^ ((row & 7) << 4)));
        }
        const int kidx = ks * 32 + lg * 8;
#pragma unroll
        for (int ct = 0; ct < 8; ++ct) {
            const int col = cb + ct * 16 + lr;
            bf[ct] = *(const short8*)(wpq + col * 128 + kidx);
        }
#pragma unroll
        for (int rt = 0; rt < 4; ++rt)
#pragma unroll
            for (int ct = 0; ct < 8; ++ct)
                acc[rt][ct] = __builtin_amdgcn_mfma_f32_16x16x32_bf16(af[rt], bf[ct], acc[rt][ct], 0, 0, 0);
    }
    // bias per-lane per ct (cols >= 256 carry b3)
    float badd[8];
#pragma unroll
    for (int ct = 0; ct < 8; ++ct) {
        const int col = cb + ct * 16 + lr;
        badd[ct] = (col >= 256) ? b3[col - 256] : 0.f;
    }
    // epilogue: LDS-staged coalesced stores (16-row chunks, stride 1040B)
#pragma unroll
    for (int rt = 0; rt < 4; ++rt) {
        __syncthreads();
#pragma unroll
        for (int ct = 0; ct < 8; ++ct) {
            const int col = cb + ct * 16 + lr;
#pragma unroll
            for (int j = 0; j < 4; ++j) {
                const int row = lg * 4 + j;
                *(__hip_bfloat16*)(A + row * 1040 + col * 2) = f2bf(acc[rt][ct][j] + badd[ct]);
            }
        }
        __syncthreads();
        const int row = t >> 4, cc = t & 15;
        const int node = n0 + rt * 16 + row;
        if (node < NN) {
#pragma unroll
            for (int pass = 0; pass < 4; ++pass) {
                const int byteoff = pass * 256 + cc * 16;
                *(uint4*)((char*)(pqb + (size_t)node * 512) + byteoff) =
                    *(const uint4*)(A + row * 1040 + byteoff);
            }
        }
    }
}

// ---------- edge: out[eid] = W4 . relu(P[src] + Q'[dst]) + b4, sorted-by-dst order ----------
__global__ __launch_bounds__(256) void edge_kernel(const int* __restrict__ ssrc,
                                                   const int* __restrict__ sdst,
                                                   const int* __restrict__ seid,
                                                   const __hip_bfloat16* __restrict__ pqb,
                                                   const float* __restrict__ W4,
                                                   const float* __restrict__ b4,
                                                   float* __restrict__ out) {
    const int i = threadIdx.x & 7;
    const int g = threadIdx.x >> 3;
    float w4r[4][8];
#pragma unroll
    for (int j = 0; j < 4; ++j)
#pragma unroll
        for (int u = 0; u < 8; ++u)
            w4r[j][u] = W4[i * 8 + j * 64 + u];
    const float b4v = b4[0];
    for (int p = blockIdx.x * 32 + g; p < NE; p += gridDim.x * 32) {
        const int s = ssrc[p], d = sdst[p], eid = seid[p];
        const char* Pp = (const char*)(pqb + (size_t)s * 512 + i * 8);
        const char* Qp = (const char*)(pqb + (size_t)d * 512 + 256 + i * 8);
        float acc = 0.f;
#pragma unroll
        for (int j = 0; j < 4; ++j) {
            const uint4 pv = *(const uint4*)(Pp + j * 128);
            const uint4 qv = *(const uint4*)(Qp + j * 128);
            const unsigned pa[4] = {pv.x, pv.y, pv.z, pv.w};
            const unsigned qa[4] = {qv.x, qv.y, qv.z, qv.w};
#pragma unroll
            for (int q4 = 0; q4 < 4; ++q4) {
                const float hlo = fmaxf(bf_lo(pa[q4]) + bf_lo(qa[q4]), 0.f);
                const float hhi = fmaxf(bf_hi(pa[q4]) + bf_hi(qa[q4]), 0.f);
                acc = fmaf(hlo, w4r[j][q4 * 2], acc);
                acc = fmaf(hhi, w4r[j][q4 * 2 + 1], acc);
            }
        }
        acc += __shfl_xor(acc, 1);
        acc += __shfl_xor(acc, 2);
        acc += __shfl_xor(acc, 4);
        if (i == 0) out[eid] = acc + b4v;
    }
}

extern "C" void kernel_launch(void* const* d_in, const int* in_sizes, int n_in,
                              void* d_out, int out_size, void* d_ws, size_t ws_size,
                              hipStream_t stream) {
    const float* x   = (const float*)d_in[0];
    const int* ei    = (const int*)d_in[1];
    const float* W1l = (const float*)d_in[2];
    const float* b1l = (const float*)d_in[3];
    const float* W1r = (const float*)d_in[4];
    const float* W2l = (const float*)d_in[5];
    const float* b2l = (const float*)d_in[6];
    const float* W2r = (const float*)d_in[7];
    const float* W3  = (const float*)d_in[8];
    const float* b3  = (const float*)d_in[9];
    const float* W4  = (const float*)d_in[10];
    const float* b4  = (const float*)d_in[11];
    float* out = (float*)d_out;

    char* ws = (char*)d_ws;
    int* cnt            = (int*)(ws);                        // 200 KB
    int* off            = (int*)(ws + 200704);
    int* cursor         = (int*)(ws + 401408);               // + bsum at cursor+NN
    int* ssrc           = (int*)(ws + 602112);               // 3.2 MB
    int* sdst           = (int*)(ws + 3802112);              // 3.2 MB
    int* seid           = (int*)(ws + 7002112);              // 3.2 MB
    __hip_bfloat16* pqb = (__hip_bfloat16*)(ws + 10202112);  // 51.2 MB (overlays h1b+ob)
    __hip_bfloat16* h1b = (__hip_bfloat16*)(ws + 23002112);  // 12.8 MB (dead before pq_gemm)
    __hip_bfloat16* ob  = (__hip_bfloat16*)(ws + 35802112);  // 25.6 MB (dead before pq_gemm)
    __hip_bfloat16* h2b = (__hip_bfloat16*)(ws + 61402112);  // 12.8 MB
    __hip_bfloat16* wpq = (__hip_bfloat16*)(ws + 74202112);  // 128 KB
    __hip_bfloat16* w12t= (__hip_bfloat16*)(ws + 74333184);  // 128 KB

    hipMemsetAsync(cnt, 0, NN * sizeof(int), stream);
    hist_kernel<<<1024, 256, 0, stream>>>(ei, cnt);
    scan_blk<<<SCAN_G, 256, 0, stream>>>(cnt, off, cursor + NN);
    scan_top<<<1, 256, 0, stream>>>(cursor + NN);
    scan_add<<<SCAN_G, 256, 0, stream>>>(off, cursor, cursor + NN);
    fill_kernel<<<1024, 256, 0, stream>>>(ei, cursor, ssrc, sdst, seid);
    prep_wpq<<<64, 256, 0, stream>>>(W3, wpq);
    prep_w12t<<<256, 256, 0, stream>>>(W1l, W1r, W2l, W2r, w12t);

    proj_gemm<true><<<(NN + 63) / 64, 256, 0, stream>>>((const void*)x, w12t, ob);
    gather_fuse<<<2048, 256, 0, stream>>>(ob, off, ssrc, b1l, h1b);
    proj_gemm<false><<<(NN + 63) / 64, 256, 0, stream>>>((const void*)h1b, w12t + 256 * 128, ob);
    gather_fuse<<<2048, 256, 0, stream>>>(ob, off, ssrc, b2l, h2b);
    pq_gemm<<<(NN + 63) / 64, 256, 0, stream>>>(h2b, wpq, b3, pqb);
    edge_kernel<<<2048, 256, 0, stream>>>(ssrc, sdst, seid, pqb, W4, b4, out);
}